// Round 15
// baseline (838.055 us; speedup 1.0000x reference)
//
#include <hip/hip_runtime.h>
#include <hip/hip_bf16.h>
#include <cstdint>

typedef __attribute__((ext_vector_type(8))) short bf16x8;
typedef __attribute__((ext_vector_type(4))) float f32x4;

typedef __attribute__((address_space(1))) const void gv_t;
typedef __attribute__((address_space(3))) void lv_t;

__device__ __forceinline__ unsigned short f2b(float f) {
  __hip_bfloat16 h = __float2bfloat16(f);
  return __builtin_bit_cast(unsigned short, h);
}
__device__ __forceinline__ float b2f(unsigned short u) {
  unsigned int x = (unsigned int)u << 16;
  return __builtin_bit_cast(float, x);
}

// ---------- cast fp32 -> bf16 (vectorized x4) ----------
__global__ __launch_bounds__(256) void k_cast(const float* __restrict__ src,
                                              unsigned short* __restrict__ dst, int n4) {
  int i = blockIdx.x * 256 + threadIdx.x;
  if (i >= n4) return;
  const float4 v = ((const float4*)src)[i];
  ushort4 o;
  o.x = f2b(v.x); o.y = f2b(v.y); o.z = f2b(v.z); o.w = f2b(v.w);
  ((ushort4*)dst)[i] = o;
}

// ---------- transpose + cast: dst[c*R + r] = bf16(src[r*C + c]) ----------
__global__ void k_transpose_cast(const float* __restrict__ src,
                                 unsigned short* __restrict__ dst, int R, int C) {
  __shared__ float tile[32][33];
  const int tx = threadIdx.x, ty = threadIdx.y;
  const int c0 = blockIdx.x * 32, r0 = blockIdx.y * 32;
#pragma unroll
  for (int i = 0; i < 32; i += 8)
    tile[ty + i][tx] = src[(long)(r0 + ty + i) * C + (c0 + tx)];
  __syncthreads();
#pragma unroll
  for (int i = 0; i < 32; i += 8)
    dst[(long)(c0 + ty + i) * R + (r0 + tx)] = f2b(tile[tx][ty + i]);
}

// ---------- merged transpose+cast for 3 same-shape weights (z selects) ----------
__global__ void k_transpose_cast3(const float* __restrict__ s0, const float* __restrict__ s1,
                                  const float* __restrict__ s2,
                                  unsigned short* __restrict__ dst, int R, int C) {
  const float* src = (blockIdx.z == 0) ? s0 : ((blockIdx.z == 1) ? s1 : s2);
  unsigned short* d = dst + (size_t)blockIdx.z * R * C;
  __shared__ float tile[32][33];
  const int tx = threadIdx.x, ty = threadIdx.y;
  const int c0 = blockIdx.x * 32, r0 = blockIdx.y * 32;
#pragma unroll
  for (int i = 0; i < 32; i += 8)
    tile[ty + i][tx] = src[(long)(r0 + ty + i) * C + (c0 + tx)];
  __syncthreads();
#pragma unroll
  for (int i = 0; i < 32; i += 8)
    d[(long)(c0 + ty + i) * R + (r0 + tx)] = f2b(tile[tx][ty + i]);
}

enum { EPI_QK = 0, EPI_VT = 1 };

// ================= 256x256 8-phase engine (T2+T3+T4+T5) — QK & VT =================
#define BAR256() do { asm volatile("" ::: "memory"); __builtin_amdgcn_s_barrier(); asm volatile("" ::: "memory"); } while (0)
#define WAITVM(n) do { asm volatile("s_waitcnt vmcnt(" #n ")" ::: "memory"); __builtin_amdgcn_sched_barrier(0); } while (0)
#define WAITLG() do { asm volatile("s_waitcnt lgkmcnt(0)" ::: "memory"); } while (0)

#define STAGE_A(tt, hw, qq)                                                                     \
  __builtin_amdgcn_global_load_lds(                                                            \
    (gv_t*)(A + (long)(m0 + (hw)*128 + (qq)*64 + rr) * lda + ((tt) << 6) + csw),               \
    (lv_t*)(&L[(((((tt)&1)*2 + (hw))*128 + (qq)*64 + rr))*64 + c0]), 16, 0, 0)

#define STAGE_B(tt, qi)                                                                         \
  __builtin_amdgcn_global_load_lds(                                                            \
    (gv_t*)(Bt + (long)(n0 + (qi)*64 + rr) * ldb + ((tt) << 6) + csw),                         \
    (lv_t*)(&L[32768 + (((((tt)&1)*2 + ((qi)>>1))*128 + ((qi)&1)*64 + rr))*64 + c0]), 16, 0, 0)

#define PHASE(slot, QR, QC) do {                                                                \
    const unsigned short* Abase = &L[((slot)*2 + wr) * 8192];                                   \
    const unsigned short* Bbase = &L[32768 + ((slot)*2 + (wc>>1)) * 8192];                      \
    bf16x8 afr[4][2], bfr[2][2];                                                                \
    _Pragma("unroll")                                                                           \
    for (int fr = 0; fr < 4; ++fr) {                                                            \
      const int rA = (QR)*64 + fr*16 + l15;                                                     \
      _Pragma("unroll")                                                                         \
      for (int kk = 0; kk < 2; ++kk) {                                                          \
        const int cA = (kk*32 + l4*8) ^ ((rA & 7) << 3);                                        \
        afr[fr][kk] = *(const bf16x8*)(Abase + rA*64 + cA);                                     \
      }                                                                                         \
    }                                                                                           \
    _Pragma("unroll")                                                                           \
    for (int fc = 0; fc < 2; ++fc) {                                                            \
      const int rB = (wc&1)*64 + (QC)*32 + fc*16 + l15;                                         \
      _Pragma("unroll")                                                                         \
      for (int kk = 0; kk < 2; ++kk) {                                                          \
        const int cB = (kk*32 + l4*8) ^ ((rB & 7) << 3);                                        \
        bfr[fc][kk] = *(const bf16x8*)(Bbase + rB*64 + cB);                                     \
      }                                                                                         \
    }                                                                                           \
    __builtin_amdgcn_s_setprio(1);                                                              \
    _Pragma("unroll")                                                                           \
    for (int fr = 0; fr < 4; ++fr)                                                              \
      _Pragma("unroll")                                                                         \
      for (int fc = 0; fc < 2; ++fc)                                                            \
        _Pragma("unroll")                                                                       \
        for (int kk = 0; kk < 2; ++kk)                                                          \
          acc[(QR)*4+fr][(QC)*2+fc] = __builtin_amdgcn_mfma_f32_16x16x32_bf16(                  \
              afr[fr][kk], bfr[fc][kk], acc[(QR)*4+fr][(QC)*2+fc], 0, 0, 0);                    \
    __builtin_amdgcn_s_setprio(0);                                                              \
  } while (0)

template <int EPI>
__global__ __launch_bounds__(512)
void k_gemm256(const unsigned short* __restrict__ A, const unsigned short* __restrict__ Bt,
               void* __restrict__ Cv, int K, int lda, int ldb, float scale) {
  const int m0 = blockIdx.y * 256;
  const int n0 = blockIdx.x * 256;
  __shared__ __align__(16) unsigned short L[65536];
  const int tid = threadIdx.x;
  const int lane = tid & 63;
  const int wid = tid >> 6;
  const int wr = wid >> 2;
  const int wc = wid & 3;
  const int l15 = lane & 15;
  const int l4 = lane >> 4;
  const int rr = tid >> 3;
  const int c0 = (tid & 7) * 8;
  const int csw = c0 ^ ((rr & 7) << 3);

  f32x4 acc[8][4] = {};
  const int NT = K >> 6;

  STAGE_A(0, 0, 0); STAGE_A(0, 1, 0); STAGE_A(0, 0, 1); STAGE_A(0, 1, 1);
  STAGE_B(0, 0); STAGE_B(0, 1); STAGE_B(0, 2); STAGE_B(0, 3);
  if (NT > 1) {
    STAGE_A(1, 0, 0); STAGE_A(1, 1, 0);
    WAITVM(2);
  } else {
    WAITVM(0);
  }
  __builtin_amdgcn_s_barrier();
  asm volatile("" ::: "memory");

  for (int t = 0; t < NT; ++t) {
    const int slot = t & 1;
    if (t + 1 < NT) { STAGE_A(t + 1, 0, 1); STAGE_A(t + 1, 1, 1); }
    PHASE(slot, 0, 0);
    BAR256();
    if (t + 1 < NT) { STAGE_B(t + 1, 0); STAGE_B(t + 1, 1); }
    PHASE(slot, 0, 1);
    BAR256();
    if (t + 1 < NT) { STAGE_B(t + 1, 2); STAGE_B(t + 1, 3); }
    if (t + 2 < NT) { STAGE_A(t + 2, 0, 0); STAGE_A(t + 2, 1, 0); }
    PHASE(slot, 1, 0);
    BAR256();
    PHASE(slot, 1, 1);
    if (t + 1 < NT) {
      if (t + 2 < NT) WAITVM(2);
      else            WAITVM(0);
      __builtin_amdgcn_s_barrier();
      asm volatile("" ::: "memory");
    }
  }

#pragma unroll
  for (int i = 0; i < 8; ++i) {
#pragma unroll
    for (int j = 0; j < 4; ++j) {
#pragma unroll
      for (int r = 0; r < 4; ++r) {
        const int row = m0 + wr * 128 + i * 16 + l4 * 4 + r;
        const int col = n0 + wc * 64 + j * 16 + l15;
        const float v = acc[i][j][r];
        if (EPI == EPI_QK) {
          unsigned short* o = (unsigned short*)Cv;
          const int sec = col >> 12;
          const int cc = col & 4095;
          const long addr = (long)sec * 33554432 +
              ((long)((row >> 10) * 8 + (cc >> 9)) * 1024 + (row & 1023)) * 512 + (cc & 511);
          o[addr] = f2b(v * scale);
        } else {  // EPI_VT
          unsigned short* o = (unsigned short*)Cv;
          const long addr = (long)((col >> 10) * 8 + (row >> 9)) * 524288 +
                            (long)(row & 511) * 1024 + (col & 1023);
          o[addr] = f2b(v);
        }
      }
    }
  }
}

// ================= fused attention, round 15: r13 base + V-direct (unbundled) =====
// r13 structure (KT=32, 64 q-rows, 8 waves, Ks dbuf padded-520, Es-40 dbuf)
// with ONE change vs r13: V never enters LDS. bv[4] loaded global->reg at
// chunk top (64B-granule coalesced: 4 lanes x contiguous 16B per e-row),
// consumed in PV after the mid barrier (QK+exp covers L2 latency).
// Vs deletion: LDS 146KB -> 77KB -> TWO blocks/CU (m114 overlap hides
// barrier drains). __launch_bounds__(512,4) caps VGPR at 128 so 2 blocks fit.
// vmcnt ledger: PV's implicit wait on bv(c) retires older K(c+1); K(c+2)
// (issued after bv) stays in flight; top WAITVM(4) semantics unchanged.
#define KLD 520     // Ks row stride (shorts): 1040B = 65*16 aligned

__device__ __forceinline__ void stage_k(const unsigned short* kg, unsigned short* dst,
                                        int c, int w, int lane) {
#pragma unroll
  for (int i = 0; i < 4; ++i) {
    const int row = i * 8 + w;
    __builtin_amdgcn_global_load_lds(
        (gv_t*)(kg + (size_t)(c * 32 + row) * 512 + lane * 8),
        (lv_t*)(dst + row * KLD + lane * 8), 16, 0, 0);
  }
}

__global__ __launch_bounds__(512, 4)
void k_attn(unsigned short* __restrict__ q,        // [64][1024][512] in/out
            const unsigned short* __restrict__ k,  // [64][1024][512]
            const unsigned short* __restrict__ vt) // [64][512][1024]
{
  __shared__ __align__(16) unsigned short Ks[2][32 * KLD];  // 65KB
  __shared__ __align__(16) unsigned short Es[2][2560];      // 10KB, stride 40
  const int bid = blockIdx.x;
  const int head = (bid & 7) * 8 + ((bid >> 3) >> 4);  // 16 same-head blocks per XCD
  const int qt = (bid >> 3) & 15;
  const int tid = threadIdx.x;
  const int w = tid >> 6, lane = tid & 63;
  const int l15 = lane & 15, l4 = lane >> 4;
  const int qf = w & 3, kf = w >> 2;

  unsigned short* qg = q + (size_t)(head * 1024 + qt * 64) * 512;
  const unsigned short* kg = k + (size_t)head * 524288;
  const unsigned short* vg = vt + (size_t)head * 524288;

  const int qrow = qf * 16 + l15;
  const int krow = kf * 16 + l15;

  // Q-hoist: lane's 16 slices of its q-row
  bf16x8 q_r[16];
#pragma unroll
  for (int ks = 0; ks < 16; ++ks)
    q_r[ks] = *(const bf16x8*)(qg + (size_t)qrow * 512 + (size_t)(ks * 4 + l4) * 8);

  // prologue: K(0), K(1)  (8 loads in flight)
  stage_k(kg, &Ks[0][0], 0, w, lane);
  stage_k(kg, &Ks[1][0], 1, w, lane);
  WAITVM(4);  // retire q_r + K(0); K(1) stays in flight
  __builtin_amdgcn_s_barrier();
  asm volatile("" ::: "memory");

  f32x4 acc[4][4] = {};
  float partial = 0.f;
  const int erow = tid >> 3;
  const int ej = tid & 7;
  const int eidx = 40 * erow + ej * 4;

  for (int c = 0; c < 32; ++c) {
    unsigned short* KsC = &Ks[c & 1][0];
    unsigned short* EsC = &Es[c & 1][0];
    if (c) {
      // top: K(c) landed (K(c+1) in flight)
      if (c < 31) { WAITVM(4); } else { WAITVM(0); }
      WAITLG();
      __builtin_amdgcn_s_barrier();
      asm volatile("" ::: "memory");
    }
    // early V(c) issue: global->reg (64B-granule coalesced; consumed in PV)
    bf16x8 bv[4];
#pragma unroll
    for (int cf = 0; cf < 4; ++cf) {
      const int e = w * 64 + cf * 16 + l15;
      bv[cf] = *(const bf16x8*)(vg + (size_t)e * 1024 + c * 32 + l4 * 8);
    }
    __builtin_amdgcn_sched_barrier(0);  // pin bv issue before QK
    // QK(c): A = q_r (regs), B = Ks (padded, linear); 2 independent chains
    f32x4 sacc0 = {0.f, 0.f, 0.f, 0.f};
    f32x4 sacc1 = {0.f, 0.f, 0.f, 0.f};
    __builtin_amdgcn_s_setprio(1);
#pragma unroll
    for (int ks = 0; ks < 16; ks += 2) {
      bf16x8 bk0 = *(const bf16x8*)(&KsC[krow * KLD + (ks * 4 + l4) * 8]);
      sacc0 = __builtin_amdgcn_mfma_f32_16x16x32_bf16(q_r[ks], bk0, sacc0, 0, 0, 0);
      bf16x8 bk1 = *(const bf16x8*)(&KsC[krow * KLD + ((ks + 1) * 4 + l4) * 8]);
      sacc1 = __builtin_amdgcn_mfma_f32_16x16x32_bf16(q_r[ks + 1], bk1, sacc1, 0, 0, 0);
    }
    __builtin_amdgcn_s_setprio(0);
#pragma unroll
    for (int r = 0; r < 4; ++r) {
      const int qq = qf * 16 + l4 * 4 + r;      // S frag: row=q, col=k
      const int kk2 = kf * 16 + l15;
      EsC[40 * qq + kk2] = f2b(__expf(sacc0[r] + sacc1[r]));
    }
    // mid barrier: publish Es; all QK(c) K-readers done
    WAITLG();
    __builtin_amdgcn_s_barrier();
    asm volatile("" ::: "memory");
    // issue K(c+2) (overwrites K(c); readers finished at mid barrier)
    if (c + 2 < 32) stage_k(kg, KsC, c + 2, w, lane);
    // rowsum partial
    {
      const ushort4 ev = *(const ushort4*)(&EsC[eidx]);
      partial += (b2f(ev.x) + b2f(ev.y)) + (b2f(ev.z) + b2f(ev.w));
    }
    // PV(c): A = Es rows, B = bv (regs). Implicit vmcnt wait for bv
    // retires K(c+1) (older); K(c+2) (younger) stays in flight.
    __builtin_amdgcn_s_setprio(1);
#pragma unroll
    for (int qf2 = 0; qf2 < 4; ++qf2) {
      const int qq = qf2 * 16 + l15;
      bf16x8 ae = *(const bf16x8*)(&EsC[40 * qq + 8 * l4]);
#pragma unroll
      for (int cf = 0; cf < 4; ++cf)
        acc[qf2][cf] = __builtin_amdgcn_mfma_f32_16x16x32_bf16(ae, bv[cf], acc[qf2][cf], 0, 0, 0);
    }
    __builtin_amdgcn_s_setprio(0);
  }

  // rowsum reduce -> 1/rs  (Ks dead; reuse as float scratch)
  __syncthreads();
  float* fs = (float*)&Ks[0][0];
  fs[tid] = partial;
  __syncthreads();
  if (tid < 64) {
    float s = 0.f;
#pragma unroll
    for (int j = 0; j < 8; ++j) s += fs[tid * 8 + j];
    fs[512 + tid] = 1.0f / s;
  }
  __syncthreads();

  // epilogue: out = acc/rs, overwrite own q rows ([bh][t][e] layout)
  // PV B-frag rows: e = w*64 + cf*16 + l15.
#pragma unroll
  for (int qf2 = 0; qf2 < 4; ++qf2) {
#pragma unroll
    for (int r = 0; r < 4; ++r) {
      const int qq = qf2 * 16 + l4 * 4 + r;
      const float iv = fs[512 + qq];
#pragma unroll
      for (int cf = 0; cf < 4; ++cf) {
        const int e = w * 64 + cf * 16 + l15;
        qg[(size_t)qq * 512 + e] = f2b(acc[qf2][cf][r] * iv);
      }
    }
  }
}

// ================= 128x128 2-phase OUT GEMM (head-split A layout) =================
__global__ __launch_bounds__(256)
void k_gemm_out(const unsigned short* __restrict__ A, const unsigned short* __restrict__ Bt,
                float* __restrict__ C, const float* __restrict__ bias) {
  const int m0 = blockIdx.y * 128;
  const int n0 = blockIdx.x * 128;
  __shared__ __align__(16) unsigned short As[2][128 * 32];
  __shared__ __align__(16) unsigned short Bs[2][128 * 32];
  const int tid = threadIdx.x;
  const int lane = tid & 63;
  const int wm = ((tid >> 6) >> 1) * 64;
  const int wn = ((tid >> 6) & 1) * 64;
  const int srow = tid >> 2;
  const int scol = (tid & 3) * 8;
  f32x4 acc[4][4] = {};

  const int row1 = m0 + srow, row2 = row1 + 64;
  const size_t hb1 = (size_t)(row1 >> 10) * 8 * 524288 + (size_t)(row1 & 1023) * 512;
  const size_t hb2 = (size_t)(row2 >> 10) * 8 * 524288 + (size_t)(row2 & 1023) * 512;
  const unsigned short* gb = Bt + (size_t)(n0 + srow) * 4096 + scol;

#define STAGEO(buf, k0) do {                                                                          \
    const size_t koffA = (size_t)((k0) >> 9) * 524288 + ((k0) & 511) + scol;                          \
    __builtin_amdgcn_global_load_lds((gv_t*)(A + hb1 + koffA), (lv_t*)(&As[buf][tid * 8]), 16, 0, 0);  \
    __builtin_amdgcn_global_load_lds((gv_t*)(A + hb2 + koffA), (lv_t*)(&As[buf][tid * 8 + 2048]), 16, 0, 0); \
    __builtin_amdgcn_global_load_lds((gv_t*)(gb + (k0)), (lv_t*)(&Bs[buf][tid * 8]), 16, 0, 0);        \
    __builtin_amdgcn_global_load_lds((gv_t*)(gb + 64L * 4096 + (k0)), (lv_t*)(&Bs[buf][tid * 8 + 2048]), 16, 0, 0); \
  } while (0)

  STAGEO(0, 0);
  for (int k0 = 0; k0 < 4096; k0 += 32) {
    const int cur = (k0 >> 5) & 1;
    __syncthreads();
    if (k0 + 32 < 4096) { STAGEO(cur ^ 1, k0 + 32); }
    const unsigned short* ap = &As[cur][(wm + (lane & 15)) * 32 + (lane >> 4) * 8];
    const unsigned short* bp = &Bs[cur][(wn + (lane & 15)) * 32 + (lane >> 4) * 8];
    bf16x8 fa[4], fb[4];
#pragma unroll
    for (int i = 0; i < 4; ++i) fa[i] = *(const bf16x8*)(ap + i * 16 * 32);
#pragma unroll
    for (int i = 0; i < 4; ++i) fb[i] = *(const bf16x8*)(bp + i * 16 * 32);
#pragma unroll
    for (int mi = 0; mi < 4; ++mi)
#pragma unroll
      for (int ni = 0; ni < 4; ++ni)
        acc[mi][ni] = __builtin_amdgcn_mfma_f32_16x16x32_bf16(fa[mi], fb[ni], acc[mi][ni], 0, 0, 0);
  }
#undef STAGEO

#pragma unroll
  for (int mi = 0; mi < 4; ++mi) {
#pragma unroll
    for (int ni = 0; ni < 4; ++ni) {
#pragma unroll
      for (int r = 0; r < 4; ++r) {
        const int row = m0 + wm + mi * 16 + ((lane >> 4) * 4 + r);
        const int col = n0 + wn + ni * 16 + (lane & 15);
        C[(long)row * 512 + col] = acc[mi][ni][r] + bias[col];
      }
    }
  }
}

extern "C" void kernel_launch(void* const* d_in, const int* in_sizes, int n_in,
                              void* d_out, int out_size, void* d_ws, size_t ws_size,
                              hipStream_t stream) {
  const float* x  = (const float*)d_in[0];
  const float* Wk = (const float*)d_in[1];
  const float* Wq = (const float*)d_in[2];
  const float* Wv = (const float*)d_in[3];
  const float* Wu = (const float*)d_in[4];
  const float* bu = (const float*)d_in[5];
  float* out = (float*)d_out;
  char* ws = (char*)d_ws;

  // ws layout: wut[0,4M) wtqkv[4M,16M) xb[16M,24M) q[24M,88M) k[88M,152M) vt[152M,216M)
  const size_t NEED = 226492416;  // 216 MB
  if (ws_size < NEED) return;

  unsigned short* wut   = (unsigned short*)(ws + 0);
  unsigned short* wtqkv = (unsigned short*)(ws + 4194304);
  unsigned short* xb    = (unsigned short*)(ws + 16777216);
  unsigned short* qb    = (unsigned short*)(ws + 25165824);  // q; attn output in-place
  unsigned short* kb    = qb + 33554432;
  unsigned short* vtb   = qb + 67108864;

  const float s4 = 0.21022410381342865f;  // 512^(-0.25)

  k_cast<<<4096, 256, 0, stream>>>(x, xb, 1048576);
  k_transpose_cast3<<<dim3(128, 16, 3), dim3(32, 8), 0, stream>>>(Wq, Wk, Wv, wtqkv, 512, 4096);
  k_transpose_cast<<<dim3(16, 128), dim3(32, 8), 0, stream>>>(Wu, wut, 4096, 512);

  // q,k = x @ [Wq|Wk] (M=8192, N=8192, K=512), scaled, scattered to [bh][t][e]
  k_gemm256<EPI_QK><<<dim3(32, 32, 1), 512, 0, stream>>>(xb, wtqkv, qb, 512, 512, 512, s4);
  // vt = Wv^T @ x^T (M=4096, N=8192, K=512) -> [bh][e][t]
  k_gemm256<EPI_VT><<<dim3(32, 16, 1), 512, 0, stream>>>(wtqkv + 4194304, xb, vtb, 512, 512, 512, 1.0f);

  // fused attention: per (head, 64-row q-tile); output over q in [bh][t][e]
  k_attn<<<1024, 512, 0, stream>>>(qb, kb, vtb);

  // out = ao @ Wu + bu (M=8192, N=512, K=4096), A in head-split layout
  k_gemm_out<<<dim3(4, 64, 1), 256, 0, stream>>>(qb, wut, out, bu);
}

// Round 16
// 524.268 us; speedup vs baseline: 1.5985x; 1.5985x over previous
//
#include <hip/hip_runtime.h>
#include <hip/hip_bf16.h>
#include <cstdint>

typedef __attribute__((ext_vector_type(8))) short bf16x8;
typedef __attribute__((ext_vector_type(4))) float f32x4;

typedef __attribute__((address_space(1))) const void gv_t;
typedef __attribute__((address_space(3))) void lv_t;

__device__ __forceinline__ unsigned short f2b(float f) {
  __hip_bfloat16 h = __float2bfloat16(f);
  return __builtin_bit_cast(unsigned short, h);
}
__device__ __forceinline__ float b2f(unsigned short u) {
  unsigned int x = (unsigned int)u << 16;
  return __builtin_bit_cast(float, x);
}

// ---------- cast fp32 -> bf16 (vectorized x4) ----------
__global__ __launch_bounds__(256) void k_cast(const float* __restrict__ src,
                                              unsigned short* __restrict__ dst, int n4) {
  int i = blockIdx.x * 256 + threadIdx.x;
  if (i >= n4) return;
  const float4 v = ((const float4*)src)[i];
  ushort4 o;
  o.x = f2b(v.x); o.y = f2b(v.y); o.z = f2b(v.z); o.w = f2b(v.w);
  ((ushort4*)dst)[i] = o;
}

// ---------- transpose + cast: dst[c*R + r] = bf16(src[r*C + c]) ----------
__global__ void k_transpose_cast(const float* __restrict__ src,
                                 unsigned short* __restrict__ dst, int R, int C) {
  __shared__ float tile[32][33];
  const int tx = threadIdx.x, ty = threadIdx.y;
  const int c0 = blockIdx.x * 32, r0 = blockIdx.y * 32;
#pragma unroll
  for (int i = 0; i < 32; i += 8)
    tile[ty + i][tx] = src[(long)(r0 + ty + i) * C + (c0 + tx)];
  __syncthreads();
#pragma unroll
  for (int i = 0; i < 32; i += 8)
    dst[(long)(c0 + ty + i) * R + (r0 + tx)] = f2b(tile[tx][ty + i]);
}

// ---------- merged transpose+cast for 3 same-shape weights (z selects) ----------
__global__ void k_transpose_cast3(const float* __restrict__ s0, const float* __restrict__ s1,
                                  const float* __restrict__ s2,
                                  unsigned short* __restrict__ dst, int R, int C) {
  const float* src = (blockIdx.z == 0) ? s0 : ((blockIdx.z == 1) ? s1 : s2);
  unsigned short* d = dst + (size_t)blockIdx.z * R * C;
  __shared__ float tile[32][33];
  const int tx = threadIdx.x, ty = threadIdx.y;
  const int c0 = blockIdx.x * 32, r0 = blockIdx.y * 32;
#pragma unroll
  for (int i = 0; i < 32; i += 8)
    tile[ty + i][tx] = src[(long)(r0 + ty + i) * C + (c0 + tx)];
  __syncthreads();
#pragma unroll
  for (int i = 0; i < 32; i += 8)
    d[(long)(c0 + ty + i) * R + (r0 + tx)] = f2b(tile[tx][ty + i]);
}

enum { EPI_QK = 0, EPI_VT = 1 };

// ================= 256x256 8-phase engine (T2+T3+T4+T5) — QK & VT =================
#define BAR256() do { asm volatile("" ::: "memory"); __builtin_amdgcn_s_barrier(); asm volatile("" ::: "memory"); } while (0)
#define WAITVM(n) do { asm volatile("s_waitcnt vmcnt(" #n ")" ::: "memory"); __builtin_amdgcn_sched_barrier(0); } while (0)
#define WAITLG() do { asm volatile("s_waitcnt lgkmcnt(0)" ::: "memory"); } while (0)

#define STAGE_A(tt, hw, qq)                                                                     \
  __builtin_amdgcn_global_load_lds(                                                            \
    (gv_t*)(A + (long)(m0 + (hw)*128 + (qq)*64 + rr) * lda + ((tt) << 6) + csw),               \
    (lv_t*)(&L[(((((tt)&1)*2 + (hw))*128 + (qq)*64 + rr))*64 + c0]), 16, 0, 0)

#define STAGE_B(tt, qi)                                                                         \
  __builtin_amdgcn_global_load_lds(                                                            \
    (gv_t*)(Bt + (long)(n0 + (qi)*64 + rr) * ldb + ((tt) << 6) + csw),                         \
    (lv_t*)(&L[32768 + (((((tt)&1)*2 + ((qi)>>1))*128 + ((qi)&1)*64 + rr))*64 + c0]), 16, 0, 0)

#define PHASE(slot, QR, QC) do {                                                                \
    const unsigned short* Abase = &L[((slot)*2 + wr) * 8192];                                   \
    const unsigned short* Bbase = &L[32768 + ((slot)*2 + (wc>>1)) * 8192];                      \
    bf16x8 afr[4][2], bfr[2][2];                                                                \
    _Pragma("unroll")                                                                           \
    for (int fr = 0; fr < 4; ++fr) {                                                            \
      const int rA = (QR)*64 + fr*16 + l15;                                                     \
      _Pragma("unroll")                                                                         \
      for (int kk = 0; kk < 2; ++kk) {                                                          \
        const int cA = (kk*32 + l4*8) ^ ((rA & 7) << 3);                                        \
        afr[fr][kk] = *(const bf16x8*)(Abase + rA*64 + cA);                                     \
      }                                                                                         \
    }                                                                                           \
    _Pragma("unroll")                                                                           \
    for (int fc = 0; fc < 2; ++fc) {                                                            \
      const int rB = (wc&1)*64 + (QC)*32 + fc*16 + l15;                                         \
      _Pragma("unroll")                                                                         \
      for (int kk = 0; kk < 2; ++kk) {                                                          \
        const int cB = (kk*32 + l4*8) ^ ((rB & 7) << 3);                                        \
        bfr[fc][kk] = *(const bf16x8*)(Bbase + rB*64 + cB);                                     \
      }                                                                                         \
    }                                                                                           \
    __builtin_amdgcn_s_setprio(1);                                                              \
    _Pragma("unroll")                                                                           \
    for (int fr = 0; fr < 4; ++fr)                                                              \
      _Pragma("unroll")                                                                         \
      for (int fc = 0; fc < 2; ++fc)                                                            \
        _Pragma("unroll")                                                                       \
        for (int kk = 0; kk < 2; ++kk)                                                          \
          acc[(QR)*4+fr][(QC)*2+fc] = __builtin_amdgcn_mfma_f32_16x16x32_bf16(                  \
              afr[fr][kk], bfr[fc][kk], acc[(QR)*4+fr][(QC)*2+fc], 0, 0, 0);                    \
    __builtin_amdgcn_s_setprio(0);                                                              \
  } while (0)

template <int EPI>
__global__ __launch_bounds__(512)
void k_gemm256(const unsigned short* __restrict__ A, const unsigned short* __restrict__ Bt,
               void* __restrict__ Cv, int K, int lda, int ldb, float scale) {
  const int m0 = blockIdx.y * 256;
  const int n0 = blockIdx.x * 256;
  __shared__ __align__(16) unsigned short L[65536];
  const int tid = threadIdx.x;
  const int lane = tid & 63;
  const int wid = tid >> 6;
  const int wr = wid >> 2;
  const int wc = wid & 3;
  const int l15 = lane & 15;
  const int l4 = lane >> 4;
  const int rr = tid >> 3;
  const int c0 = (tid & 7) * 8;
  const int csw = c0 ^ ((rr & 7) << 3);

  f32x4 acc[8][4] = {};
  const int NT = K >> 6;

  STAGE_A(0, 0, 0); STAGE_A(0, 1, 0); STAGE_A(0, 0, 1); STAGE_A(0, 1, 1);
  STAGE_B(0, 0); STAGE_B(0, 1); STAGE_B(0, 2); STAGE_B(0, 3);
  if (NT > 1) {
    STAGE_A(1, 0, 0); STAGE_A(1, 1, 0);
    WAITVM(2);
  } else {
    WAITVM(0);
  }
  __builtin_amdgcn_s_barrier();
  asm volatile("" ::: "memory");

  for (int t = 0; t < NT; ++t) {
    const int slot = t & 1;
    if (t + 1 < NT) { STAGE_A(t + 1, 0, 1); STAGE_A(t + 1, 1, 1); }
    PHASE(slot, 0, 0);
    BAR256();
    if (t + 1 < NT) { STAGE_B(t + 1, 0); STAGE_B(t + 1, 1); }
    PHASE(slot, 0, 1);
    BAR256();
    if (t + 1 < NT) { STAGE_B(t + 1, 2); STAGE_B(t + 1, 3); }
    if (t + 2 < NT) { STAGE_A(t + 2, 0, 0); STAGE_A(t + 2, 1, 0); }
    PHASE(slot, 1, 0);
    BAR256();
    PHASE(slot, 1, 1);
    if (t + 1 < NT) {
      if (t + 2 < NT) WAITVM(2);
      else            WAITVM(0);
      __builtin_amdgcn_s_barrier();
      asm volatile("" ::: "memory");
    }
  }

#pragma unroll
  for (int i = 0; i < 8; ++i) {
#pragma unroll
    for (int j = 0; j < 4; ++j) {
#pragma unroll
      for (int r = 0; r < 4; ++r) {
        const int row = m0 + wr * 128 + i * 16 + l4 * 4 + r;
        const int col = n0 + wc * 64 + j * 16 + l15;
        const float v = acc[i][j][r];
        if (EPI == EPI_QK) {
          unsigned short* o = (unsigned short*)Cv;
          const int sec = col >> 12;
          const int cc = col & 4095;
          const long addr = (long)sec * 33554432 +
              ((long)((row >> 10) * 8 + (cc >> 9)) * 1024 + (row & 1023)) * 512 + (cc & 511);
          o[addr] = f2b(v * scale);
        } else {  // EPI_VT
          unsigned short* o = (unsigned short*)Cv;
          const long addr = (long)((col >> 10) * 8 + (row >> 9)) * 524288 +
                            (long)(row & 511) * 1024 + (col & 1023);
          o[addr] = f2b(v);
        }
      }
    }
  }
}

// ================= fused attention, round 16: V-direct at NATURAL VGPR =========
// Identical to round 15 except __launch_bounds__(512) — no min-waves arg.
// r15's (512,4) forced VGPR=64 -> q_r[16] spilled to scratch (FETCH 1.7GB,
// 611us). Natural VGPR for this body ~112-125; if <=128 the HW runs
// 2 blocks/CU (LDS 77KB) per m69's occupancy steps — the intended effect.
#define KLD 520     // Ks row stride (shorts): 1040B = 65*16 aligned

__device__ __forceinline__ void stage_k(const unsigned short* kg, unsigned short* dst,
                                        int c, int w, int lane) {
#pragma unroll
  for (int i = 0; i < 4; ++i) {
    const int row = i * 8 + w;
    __builtin_amdgcn_global_load_lds(
        (gv_t*)(kg + (size_t)(c * 32 + row) * 512 + lane * 8),
        (lv_t*)(dst + row * KLD + lane * 8), 16, 0, 0);
  }
}

__global__ __launch_bounds__(512)
void k_attn(unsigned short* __restrict__ q,        // [64][1024][512] in/out
            const unsigned short* __restrict__ k,  // [64][1024][512]
            const unsigned short* __restrict__ vt) // [64][512][1024]
{
  __shared__ __align__(16) unsigned short Ks[2][32 * KLD];  // 65KB
  __shared__ __align__(16) unsigned short Es[2][2560];      // 10KB, stride 40
  const int bid = blockIdx.x;
  const int head = (bid & 7) * 8 + ((bid >> 3) >> 4);  // 16 same-head blocks per XCD
  const int qt = (bid >> 3) & 15;
  const int tid = threadIdx.x;
  const int w = tid >> 6, lane = tid & 63;
  const int l15 = lane & 15, l4 = lane >> 4;
  const int qf = w & 3, kf = w >> 2;

  unsigned short* qg = q + (size_t)(head * 1024 + qt * 64) * 512;
  const unsigned short* kg = k + (size_t)head * 524288;
  const unsigned short* vg = vt + (size_t)head * 524288;

  const int qrow = qf * 16 + l15;
  const int krow = kf * 16 + l15;

  // Q-hoist: lane's 16 slices of its q-row
  bf16x8 q_r[16];
#pragma unroll
  for (int ks = 0; ks < 16; ++ks)
    q_r[ks] = *(const bf16x8*)(qg + (size_t)qrow * 512 + (size_t)(ks * 4 + l4) * 8);

  // prologue: K(0), K(1)  (8 loads in flight)
  stage_k(kg, &Ks[0][0], 0, w, lane);
  stage_k(kg, &Ks[1][0], 1, w, lane);
  WAITVM(4);  // retire q_r + K(0); K(1) stays in flight
  __builtin_amdgcn_s_barrier();
  asm volatile("" ::: "memory");

  f32x4 acc[4][4] = {};
  float partial = 0.f;
  const int erow = tid >> 3;
  const int ej = tid & 7;
  const int eidx = 40 * erow + ej * 4;

  for (int c = 0; c < 32; ++c) {
    unsigned short* KsC = &Ks[c & 1][0];
    unsigned short* EsC = &Es[c & 1][0];
    if (c) {
      // top: K(c) landed (retired by prev PV's bv wait); K(c+1) in flight
      if (c < 31) { WAITVM(4); } else { WAITVM(0); }
      WAITLG();
      __builtin_amdgcn_s_barrier();
      asm volatile("" ::: "memory");
    }
    // early V(c) issue: global->reg (64B-granule coalesced; consumed in PV)
    bf16x8 bv[4];
#pragma unroll
    for (int cf = 0; cf < 4; ++cf) {
      const int e = w * 64 + cf * 16 + l15;
      bv[cf] = *(const bf16x8*)(vg + (size_t)e * 1024 + c * 32 + l4 * 8);
    }
    __builtin_amdgcn_sched_barrier(0);  // pin bv issue before QK
    // QK(c): A = q_r (regs), B = Ks (padded, linear); 2 independent chains
    f32x4 sacc0 = {0.f, 0.f, 0.f, 0.f};
    f32x4 sacc1 = {0.f, 0.f, 0.f, 0.f};
    __builtin_amdgcn_s_setprio(1);
#pragma unroll
    for (int ks = 0; ks < 16; ks += 2) {
      bf16x8 bk0 = *(const bf16x8*)(&KsC[krow * KLD + (ks * 4 + l4) * 8]);
      sacc0 = __builtin_amdgcn_mfma_f32_16x16x32_bf16(q_r[ks], bk0, sacc0, 0, 0, 0);
      bf16x8 bk1 = *(const bf16x8*)(&KsC[krow * KLD + ((ks + 1) * 4 + l4) * 8]);
      sacc1 = __builtin_amdgcn_mfma_f32_16x16x32_bf16(q_r[ks + 1], bk1, sacc1, 0, 0, 0);
    }
    __builtin_amdgcn_s_setprio(0);
#pragma unroll
    for (int r = 0; r < 4; ++r) {
      const int qq = qf * 16 + l4 * 4 + r;      // S frag: row=q, col=k
      const int kk2 = kf * 16 + l15;
      EsC[40 * qq + kk2] = f2b(__expf(sacc0[r] + sacc1[r]));
    }
    // mid barrier: publish Es; all QK(c) K-readers done
    WAITLG();
    __builtin_amdgcn_s_barrier();
    asm volatile("" ::: "memory");
    // issue K(c+2) (overwrites K(c); readers finished at mid barrier)
    if (c + 2 < 32) stage_k(kg, KsC, c + 2, w, lane);
    // rowsum partial
    {
      const ushort4 ev = *(const ushort4*)(&EsC[eidx]);
      partial += (b2f(ev.x) + b2f(ev.y)) + (b2f(ev.z) + b2f(ev.w));
    }
    // PV(c): A = Es rows, B = bv (regs). Implicit vmcnt wait for bv
    // retires K(c+1) (older); K(c+2) (younger) stays in flight.
    __builtin_amdgcn_s_setprio(1);
#pragma unroll
    for (int qf2 = 0; qf2 < 4; ++qf2) {
      const int qq = qf2 * 16 + l15;
      bf16x8 ae = *(const bf16x8*)(&EsC[40 * qq + 8 * l4]);
#pragma unroll
      for (int cf = 0; cf < 4; ++cf)
        acc[qf2][cf] = __builtin_amdgcn_mfma_f32_16x16x32_bf16(ae, bv[cf], acc[qf2][cf], 0, 0, 0);
    }
    __builtin_amdgcn_s_setprio(0);
  }

  // rowsum reduce -> 1/rs  (Ks dead; reuse as float scratch)
  __syncthreads();
  float* fs = (float*)&Ks[0][0];
  fs[tid] = partial;
  __syncthreads();
  if (tid < 64) {
    float s = 0.f;
#pragma unroll
    for (int j = 0; j < 8; ++j) s += fs[tid * 8 + j];
    fs[512 + tid] = 1.0f / s;
  }
  __syncthreads();

  // epilogue: out = acc/rs, overwrite own q rows ([bh][t][e] layout)
  // PV B-frag rows: e = w*64 + cf*16 + l15.
#pragma unroll
  for (int qf2 = 0; qf2 < 4; ++qf2) {
#pragma unroll
    for (int r = 0; r < 4; ++r) {
      const int qq = qf2 * 16 + l4 * 4 + r;
      const float iv = fs[512 + qq];
#pragma unroll
      for (int cf = 0; cf < 4; ++cf) {
        const int e = w * 64 + cf * 16 + l15;
        qg[(size_t)qq * 512 + e] = f2b(acc[qf2][cf][r] * iv);
      }
    }
  }
}

// ================= 128x128 2-phase OUT GEMM (head-split A layout) =================
__global__ __launch_bounds__(256)
void k_gemm_out(const unsigned short* __restrict__ A, const unsigned short* __restrict__ Bt,
                float* __restrict__ C, const float* __restrict__ bias) {
  const int m0 = blockIdx.y * 128;
  const int n0 = blockIdx.x * 128;
  __shared__ __align__(16) unsigned short As[2][128 * 32];
  __shared__ __align__(16) unsigned short Bs[2][128 * 32];
  const int tid = threadIdx.x;
  const int lane = tid & 63;
  const int wm = ((tid >> 6) >> 1) * 64;
  const int wn = ((tid >> 6) & 1) * 64;
  const int srow = tid >> 2;
  const int scol = (tid & 3) * 8;
  f32x4 acc[4][4] = {};

  const int row1 = m0 + srow, row2 = row1 + 64;
  const size_t hb1 = (size_t)(row1 >> 10) * 8 * 524288 + (size_t)(row1 & 1023) * 512;
  const size_t hb2 = (size_t)(row2 >> 10) * 8 * 524288 + (size_t)(row2 & 1023) * 512;
  const unsigned short* gb = Bt + (size_t)(n0 + srow) * 4096 + scol;

#define STAGEO(buf, k0) do {                                                                          \
    const size_t koffA = (size_t)((k0) >> 9) * 524288 + ((k0) & 511) + scol;                          \
    __builtin_amdgcn_global_load_lds((gv_t*)(A + hb1 + koffA), (lv_t*)(&As[buf][tid * 8]), 16, 0, 0);  \
    __builtin_amdgcn_global_load_lds((gv_t*)(A + hb2 + koffA), (lv_t*)(&As[buf][tid * 8 + 2048]), 16, 0, 0); \
    __builtin_amdgcn_global_load_lds((gv_t*)(gb + (k0)), (lv_t*)(&Bs[buf][tid * 8]), 16, 0, 0);        \
    __builtin_amdgcn_global_load_lds((gv_t*)(gb + 64L * 4096 + (k0)), (lv_t*)(&Bs[buf][tid * 8 + 2048]), 16, 0, 0); \
  } while (0)

  STAGEO(0, 0);
  for (int k0 = 0; k0 < 4096; k0 += 32) {
    const int cur = (k0 >> 5) & 1;
    __syncthreads();
    if (k0 + 32 < 4096) { STAGEO(cur ^ 1, k0 + 32); }
    const unsigned short* ap = &As[cur][(wm + (lane & 15)) * 32 + (lane >> 4) * 8];
    const unsigned short* bp = &Bs[cur][(wn + (lane & 15)) * 32 + (lane >> 4) * 8];
    bf16x8 fa[4], fb[4];
#pragma unroll
    for (int i = 0; i < 4; ++i) fa[i] = *(const bf16x8*)(ap + i * 16 * 32);
#pragma unroll
    for (int i = 0; i < 4; ++i) fb[i] = *(const bf16x8*)(bp + i * 16 * 32);
#pragma unroll
    for (int mi = 0; mi < 4; ++mi)
#pragma unroll
      for (int ni = 0; ni < 4; ++ni)
        acc[mi][ni] = __builtin_amdgcn_mfma_f32_16x16x32_bf16(fa[mi], fb[ni], acc[mi][ni], 0, 0, 0);
  }
#undef STAGEO

#pragma unroll
  for (int mi = 0; mi < 4; ++mi) {
#pragma unroll
    for (int ni = 0; ni < 4; ++ni) {
#pragma unroll
      for (int r = 0; r < 4; ++r) {
        const int row = m0 + wm + mi * 16 + ((lane >> 4) * 4 + r);
        const int col = n0 + wn + ni * 16 + (lane & 15);
        C[(long)row * 512 + col] = acc[mi][ni][r] + bias[col];
      }
    }
  }
}

extern "C" void kernel_launch(void* const* d_in, const int* in_sizes, int n_in,
                              void* d_out, int out_size, void* d_ws, size_t ws_size,
                              hipStream_t stream) {
  const float* x  = (const float*)d_in[0];
  const float* Wk = (const float*)d_in[1];
  const float* Wq = (const float*)d_in[2];
  const float* Wv = (const float*)d_in[3];
  const float* Wu = (const float*)d_in[4];
  const float* bu = (const float*)d_in[5];
  float* out = (float*)d_out;
  char* ws = (char*)d_ws;

  // ws layout: wut[0,4M) wtqkv[4M,16M) xb[16M,24M) q[24M,88M) k[88M,152M) vt[152M,216M)
  const size_t NEED = 226492416;  // 216 MB
  if (ws_size < NEED) return;

  unsigned short* wut   = (unsigned short*)(ws + 0);
  unsigned short* wtqkv = (unsigned short*)(ws + 4194304);
  unsigned short* xb    = (unsigned short*)(ws + 16777216);
  unsigned short* qb    = (unsigned short*)(ws + 25165824);  // q; attn output in-place
  unsigned short* kb    = qb + 33554432;
  unsigned short* vtb   = qb + 67108864;

  const float s4 = 0.21022410381342865f;  // 512^(-0.25)

  k_cast<<<4096, 256, 0, stream>>>(x, xb, 1048576);
  k_transpose_cast3<<<dim3(128, 16, 3), dim3(32, 8), 0, stream>>>(Wq, Wk, Wv, wtqkv, 512, 4096);
  k_transpose_cast<<<dim3(16, 128), dim3(32, 8), 0, stream>>>(Wu, wut, 4096, 512);

  // q,k = x @ [Wq|Wk] (M=8192, N=8192, K=512), scaled, scattered to [bh][t][e]
  k_gemm256<EPI_QK><<<dim3(32, 32, 1), 512, 0, stream>>>(xb, wtqkv, qb, 512, 512, 512, s4);
  // vt = Wv^T @ x^T (M=4096, N=8192, K=512) -> [bh][e][t]
  k_gemm256<EPI_VT><<<dim3(32, 16, 1), 512, 0, stream>>>(wtqkv + 4194304, xb, vtb, 512, 512, 512, 1.0f);

  // fused attention: per (head, 64-row q-tile); output over q in [bh][t][e]
  k_attn<<<1024, 512, 0, stream>>>(qb, kb, vtb);

  // out = ao @ Wu + bu (M=8192, N=512, K=4096), A in head-split layout
  k_gemm_out<<<dim3(4, 64, 1), 256, 0, stream>>>(qb, wut, out, bu);
}

// Round 17
// 474.897 us; speedup vs baseline: 1.7647x; 1.1040x over previous
//
#include <hip/hip_runtime.h>
#include <hip/hip_bf16.h>
#include <cstdint>

typedef __attribute__((ext_vector_type(8))) short bf16x8;
typedef __attribute__((ext_vector_type(4))) float f32x4;

typedef __attribute__((address_space(1))) const void gv_t;
typedef __attribute__((address_space(3))) void lv_t;

__device__ __forceinline__ unsigned short f2b(float f) {
  __hip_bfloat16 h = __float2bfloat16(f);
  return __builtin_bit_cast(unsigned short, h);
}
__device__ __forceinline__ float b2f(unsigned short u) {
  unsigned int x = (unsigned int)u << 16;
  return __builtin_bit_cast(float, x);
}

// ---------- cast fp32 -> bf16 (vectorized x4) ----------
__global__ __launch_bounds__(256) void k_cast(const float* __restrict__ src,
                                              unsigned short* __restrict__ dst, int n4) {
  int i = blockIdx.x * 256 + threadIdx.x;
  if (i >= n4) return;
  const float4 v = ((const float4*)src)[i];
  ushort4 o;
  o.x = f2b(v.x); o.y = f2b(v.y); o.z = f2b(v.z); o.w = f2b(v.w);
  ((ushort4*)dst)[i] = o;
}

// ---------- transpose + cast: dst[c*R + r] = bf16(src[r*C + c]) ----------
__global__ void k_transpose_cast(const float* __restrict__ src,
                                 unsigned short* __restrict__ dst, int R, int C) {
  __shared__ float tile[32][33];
  const int tx = threadIdx.x, ty = threadIdx.y;
  const int c0 = blockIdx.x * 32, r0 = blockIdx.y * 32;
#pragma unroll
  for (int i = 0; i < 32; i += 8)
    tile[ty + i][tx] = src[(long)(r0 + ty + i) * C + (c0 + tx)];
  __syncthreads();
#pragma unroll
  for (int i = 0; i < 32; i += 8)
    dst[(long)(c0 + ty + i) * R + (r0 + tx)] = f2b(tile[tx][ty + i]);
}

// ---------- merged transpose+cast for 3 same-shape weights (z selects) ----------
__global__ void k_transpose_cast3(const float* __restrict__ s0, const float* __restrict__ s1,
                                  const float* __restrict__ s2,
                                  unsigned short* __restrict__ dst, int R, int C) {
  const float* src = (blockIdx.z == 0) ? s0 : ((blockIdx.z == 1) ? s1 : s2);
  unsigned short* d = dst + (size_t)blockIdx.z * R * C;
  __shared__ float tile[32][33];
  const int tx = threadIdx.x, ty = threadIdx.y;
  const int c0 = blockIdx.x * 32, r0 = blockIdx.y * 32;
#pragma unroll
  for (int i = 0; i < 32; i += 8)
    tile[ty + i][tx] = src[(long)(r0 + ty + i) * C + (c0 + tx)];
  __syncthreads();
#pragma unroll
  for (int i = 0; i < 32; i += 8)
    d[(long)(c0 + ty + i) * R + (r0 + tx)] = f2b(tile[tx][ty + i]);
}

enum { EPI_QK = 0, EPI_VT = 1 };

// ================= 256x256 8-phase engine (T2+T3+T4+T5) — QK & VT =================
#define BAR256() do { asm volatile("" ::: "memory"); __builtin_amdgcn_s_barrier(); asm volatile("" ::: "memory"); } while (0)
#define WAITVM(n) do { asm volatile("s_waitcnt vmcnt(" #n ")" ::: "memory"); __builtin_amdgcn_sched_barrier(0); } while (0)
#define WAITLG() do { asm volatile("s_waitcnt lgkmcnt(0)" ::: "memory"); } while (0)

#define STAGE_A(tt, hw, qq)                                                                     \
  __builtin_amdgcn_global_load_lds(                                                            \
    (gv_t*)(A + (long)(m0 + (hw)*128 + (qq)*64 + rr) * lda + ((tt) << 6) + csw),               \
    (lv_t*)(&L[(((((tt)&1)*2 + (hw))*128 + (qq)*64 + rr))*64 + c0]), 16, 0, 0)

#define STAGE_B(tt, qi)                                                                         \
  __builtin_amdgcn_global_load_lds(                                                            \
    (gv_t*)(Bt + (long)(n0 + (qi)*64 + rr) * ldb + ((tt) << 6) + csw),                         \
    (lv_t*)(&L[32768 + (((((tt)&1)*2 + ((qi)>>1))*128 + ((qi)&1)*64 + rr))*64 + c0]), 16, 0, 0)

#define PHASE(slot, QR, QC) do {                                                                \
    const unsigned short* Abase = &L[((slot)*2 + wr) * 8192];                                   \
    const unsigned short* Bbase = &L[32768 + ((slot)*2 + (wc>>1)) * 8192];                      \
    bf16x8 afr[4][2], bfr[2][2];                                                                \
    _Pragma("unroll")                                                                           \
    for (int fr = 0; fr < 4; ++fr) {                                                            \
      const int rA = (QR)*64 + fr*16 + l15;                                                     \
      _Pragma("unroll")                                                                         \
      for (int kk = 0; kk < 2; ++kk) {                                                          \
        const int cA = (kk*32 + l4*8) ^ ((rA & 7) << 3);                                        \
        afr[fr][kk] = *(const bf16x8*)(Abase + rA*64 + cA);                                     \
      }                                                                                         \
    }                                                                                           \
    _Pragma("unroll")                                                                           \
    for (int fc = 0; fc < 2; ++fc) {                                                            \
      const int rB = (wc&1)*64 + (QC)*32 + fc*16 + l15;                                         \
      _Pragma("unroll")                                                                         \
      for (int kk = 0; kk < 2; ++kk) {                                                          \
        const int cB = (kk*32 + l4*8) ^ ((rB & 7) << 3);                                        \
        bfr[fc][kk] = *(const bf16x8*)(Bbase + rB*64 + cB);                                     \
      }                                                                                         \
    }                                                                                           \
    __builtin_amdgcn_s_setprio(1);                                                              \
    _Pragma("unroll")                                                                           \
    for (int fr = 0; fr < 4; ++fr)                                                              \
      _Pragma("unroll")                                                                         \
      for (int fc = 0; fc < 2; ++fc)                                                            \
        _Pragma("unroll")                                                                       \
        for (int kk = 0; kk < 2; ++kk)                                                          \
          acc[(QR)*4+fr][(QC)*2+fc] = __builtin_amdgcn_mfma_f32_16x16x32_bf16(                  \
              afr[fr][kk], bfr[fc][kk], acc[(QR)*4+fr][(QC)*2+fc], 0, 0, 0);                    \
    __builtin_amdgcn_s_setprio(0);                                                              \
  } while (0)

template <int EPI>
__global__ __launch_bounds__(512)
void k_gemm256(const unsigned short* __restrict__ A, const unsigned short* __restrict__ Bt,
               void* __restrict__ Cv, int K, int lda, int ldb, float scale) {
  // T1 bijective XCD swizzle (grid counts are %8==0: QK 1024, VT 512 blocks)
  const int nwg = gridDim.x * gridDim.y;
  const int bid0 = blockIdx.y * gridDim.x + blockIdx.x;
  const int cpx = nwg >> 3;
  const int sbid = (bid0 & 7) * cpx + (bid0 >> 3);
  const int m0 = (sbid / gridDim.x) * 256;
  const int n0 = (sbid % gridDim.x) * 256;
  __shared__ __align__(16) unsigned short L[65536];
  const int tid = threadIdx.x;
  const int lane = tid & 63;
  const int wid = tid >> 6;
  const int wr = wid >> 2;
  const int wc = wid & 3;
  const int l15 = lane & 15;
  const int l4 = lane >> 4;
  const int rr = tid >> 3;
  const int c0 = (tid & 7) * 8;
  const int csw = c0 ^ ((rr & 7) << 3);

  f32x4 acc[8][4] = {};
  const int NT = K >> 6;

  STAGE_A(0, 0, 0); STAGE_A(0, 1, 0); STAGE_A(0, 0, 1); STAGE_A(0, 1, 1);
  STAGE_B(0, 0); STAGE_B(0, 1); STAGE_B(0, 2); STAGE_B(0, 3);
  if (NT > 1) {
    STAGE_A(1, 0, 0); STAGE_A(1, 1, 0);
    WAITVM(2);
  } else {
    WAITVM(0);
  }
  __builtin_amdgcn_s_barrier();
  asm volatile("" ::: "memory");

  for (int t = 0; t < NT; ++t) {
    const int slot = t & 1;
    if (t + 1 < NT) { STAGE_A(t + 1, 0, 1); STAGE_A(t + 1, 1, 1); }
    PHASE(slot, 0, 0);
    BAR256();
    if (t + 1 < NT) { STAGE_B(t + 1, 0); STAGE_B(t + 1, 1); }
    PHASE(slot, 0, 1);
    BAR256();
    if (t + 1 < NT) { STAGE_B(t + 1, 2); STAGE_B(t + 1, 3); }
    if (t + 2 < NT) { STAGE_A(t + 2, 0, 0); STAGE_A(t + 2, 1, 0); }
    PHASE(slot, 1, 0);
    BAR256();
    PHASE(slot, 1, 1);
    if (t + 1 < NT) {
      if (t + 2 < NT) WAITVM(2);
      else            WAITVM(0);
      __builtin_amdgcn_s_barrier();
      asm volatile("" ::: "memory");
    }
  }

#pragma unroll
  for (int i = 0; i < 8; ++i) {
#pragma unroll
    for (int j = 0; j < 4; ++j) {
#pragma unroll
      for (int r = 0; r < 4; ++r) {
        const int row = m0 + wr * 128 + i * 16 + l4 * 4 + r;
        const int col = n0 + wc * 64 + j * 16 + l15;
        const float v = acc[i][j][r];
        if (EPI == EPI_QK) {
          unsigned short* o = (unsigned short*)Cv;
          const int sec = col >> 12;
          const int cc = col & 4095;
          const long addr = (long)sec * 33554432 +
              ((long)((row >> 10) * 8 + (cc >> 9)) * 1024 + (row & 1023)) * 512 + (cc & 511);
          o[addr] = f2b(v * scale);
        } else {  // EPI_VT
          unsigned short* o = (unsigned short*)Cv;
          const long addr = (long)((col >> 10) * 8 + (row >> 9)) * 524288 +
                            (long)(row & 511) * 1024 + (col & 1023);
          o[addr] = f2b(v);
        }
      }
    }
  }
}

// ================= fused attention: r13 exact (best measured: 262 us) =================
// KT=32, 64 q-rows, 8 waves; Ks dbuf padded-520 (aligned, 8-touches/bank);
// Vs grouped 544-stride; Es 40-stride; counted vmcnt(4); Q hoisted to regs.
#define KLD 520     // Ks padded row stride (shorts), 16B-aligned
#define VGRP 544    // Vs group stride (shorts)

__device__ __forceinline__ void stage_k(const unsigned short* kg, unsigned short* dst,
                                        int c, int w, int lane) {
#pragma unroll
  for (int i = 0; i < 4; ++i) {
    const int row = i * 8 + w;
    __builtin_amdgcn_global_load_lds(
        (gv_t*)(kg + (size_t)(c * 32 + row) * 512 + lane * 8),
        (lv_t*)(dst + row * KLD + lane * 8), 16, 0, 0);
  }
}
__device__ __forceinline__ void stage_v(const unsigned short* vg, unsigned short* dst,
                                        int c, int w, int lane) {
#pragma unroll
  for (int i = 0; i < 4; ++i) {
    const int G = i * 8 + w;                 // group = 16 e-rows
    const int e = G * 16 + (lane >> 2);
    __builtin_amdgcn_global_load_lds(
        (gv_t*)(vg + (size_t)e * 1024 + c * 32 + (lane & 3) * 8),
        (lv_t*)(dst + G * VGRP + lane * 8), 16, 0, 0);
  }
}

__global__ __launch_bounds__(512)
void k_attn(unsigned short* __restrict__ q,        // [64][1024][512] in/out
            const unsigned short* __restrict__ k,  // [64][1024][512]
            const unsigned short* __restrict__ vt) // [64][512][1024]
{
  __shared__ __align__(16) unsigned short Ks[2][32 * KLD];   // 65KB
  __shared__ __align__(16) unsigned short Vs[2][32 * VGRP];  // 68KB
  __shared__ __align__(16) unsigned short Es[2][2560];       // 10KB, stride 40
  const int bid = blockIdx.x;
  const int head = (bid & 7) * 8 + ((bid >> 3) >> 4);  // 16 same-head blocks per XCD
  const int qt = (bid >> 3) & 15;
  const int tid = threadIdx.x;
  const int w = tid >> 6, lane = tid & 63;
  const int l15 = lane & 15, l4 = lane >> 4;
  const int qf = w & 3, kf = w >> 2;

  unsigned short* qg = q + (size_t)(head * 1024 + qt * 64) * 512;
  const unsigned short* kg = k + (size_t)head * 524288;
  const unsigned short* vg = vt + (size_t)head * 524288;

  const int qrow = qf * 16 + l15;
  const int krow = kf * 16 + l15;

  // Q-hoist: lane's 16 slices of its q-row
  bf16x8 q_r[16];
#pragma unroll
  for (int ks = 0; ks < 16; ++ks)
    q_r[ks] = *(const bf16x8*)(qg + (size_t)qrow * 512 + (size_t)(ks * 4 + l4) * 8);

  // prologue: K(0), V(0), K(1)  (12 loads in flight)
  stage_k(kg, &Ks[0][0], 0, w, lane);
  stage_v(vg, &Vs[0][0], 0, w, lane);
  stage_k(kg, &Ks[1][0], 1, w, lane);

  f32x4 acc[4][4] = {};
  float partial = 0.f;
  const int erow = tid >> 3;
  const int ej = tid & 7;
  const int eidx = 40 * erow + ej * 4;

  for (int c = 0; c < 32; ++c) {
    unsigned short* KsC = &Ks[c & 1][0];
    unsigned short* VsC = &Vs[c & 1][0];
    unsigned short* EsC = &Es[c & 1][0];
    // top barrier: K(c),V(c) landed; K(c+1) stays in flight
    if (c < 31) { WAITVM(4); } else { WAITVM(0); }
    WAITLG();
    __builtin_amdgcn_s_barrier();
    asm volatile("" ::: "memory");
    // issue V(c+1) (overwrites V(c-1); readers finished before this barrier)
    if (c + 1 < 32) stage_v(vg, &Vs[(c + 1) & 1][0], c + 1, w, lane);
    // QK(c): A = q_r (regs), B = Ks (padded, linear); 2 independent chains
    f32x4 sacc0 = {0.f, 0.f, 0.f, 0.f};
    f32x4 sacc1 = {0.f, 0.f, 0.f, 0.f};
    __builtin_amdgcn_s_setprio(1);
#pragma unroll
    for (int ks = 0; ks < 16; ks += 2) {
      bf16x8 bk0 = *(const bf16x8*)(&KsC[krow * KLD + (ks * 4 + l4) * 8]);
      sacc0 = __builtin_amdgcn_mfma_f32_16x16x32_bf16(q_r[ks], bk0, sacc0, 0, 0, 0);
      bf16x8 bk1 = *(const bf16x8*)(&KsC[krow * KLD + ((ks + 1) * 4 + l4) * 8]);
      sacc1 = __builtin_amdgcn_mfma_f32_16x16x32_bf16(q_r[ks + 1], bk1, sacc1, 0, 0, 0);
    }
    __builtin_amdgcn_s_setprio(0);
#pragma unroll
    for (int r = 0; r < 4; ++r) {
      const int qq = qf * 16 + l4 * 4 + r;      // S frag: row=q, col=k
      const int kk2 = kf * 16 + l15;
      EsC[40 * qq + kk2] = f2b(__expf(sacc0[r] + sacc1[r]));
    }
    // mid barrier: publish Es; all QK(c) K-readers done
    WAITLG();
    __builtin_amdgcn_s_barrier();
    asm volatile("" ::: "memory");
    // issue K(c+2) (overwrites K(c); readers finished at mid barrier)
    if (c + 2 < 32) stage_k(kg, KsC, c + 2, w, lane);
    // rowsum partial
    {
      const ushort4 ev = *(const ushort4*)(&EsC[eidx]);
      partial += (b2f(ev.x) + b2f(ev.y)) + (b2f(ev.z) + b2f(ev.w));
    }
    // PV(c): grouped Vs reads (group = w*4+cf, row = l15, slice l4)
    bf16x8 bv[4];
#pragma unroll
    for (int cf = 0; cf < 4; ++cf) {
      const int G = w * 4 + cf;
      bv[cf] = *(const bf16x8*)(&VsC[G * VGRP + l15 * 32 + l4 * 8]);
    }
    __builtin_amdgcn_s_setprio(1);
#pragma unroll
    for (int qf2 = 0; qf2 < 4; ++qf2) {
      const int qq = qf2 * 16 + l15;
      bf16x8 ae = *(const bf16x8*)(&EsC[40 * qq + 8 * l4]);
#pragma unroll
      for (int cf = 0; cf < 4; ++cf)
        acc[qf2][cf] = __builtin_amdgcn_mfma_f32_16x16x32_bf16(ae, bv[cf], acc[qf2][cf], 0, 0, 0);
    }
    __builtin_amdgcn_s_setprio(0);
  }

  // rowsum reduce -> 1/rs  (Ks dead; reuse as float scratch)
  __syncthreads();
  float* fs = (float*)&Ks[0][0];
  fs[tid] = partial;
  __syncthreads();
  if (tid < 64) {
    float s = 0.f;
#pragma unroll
    for (int j = 0; j < 8; ++j) s += fs[tid * 8 + j];
    fs[512 + tid] = 1.0f / s;
  }
  __syncthreads();

  // epilogue: out = acc/rs, overwrite own q rows ([bh][t][e] layout)
  // PV B-frag = V rows of group G=w*4+cf, row l15 -> e = G*16 + l15.
#pragma unroll
  for (int qf2 = 0; qf2 < 4; ++qf2) {
#pragma unroll
    for (int r = 0; r < 4; ++r) {
      const int qq = qf2 * 16 + l4 * 4 + r;
      const float iv = fs[512 + qq];
#pragma unroll
      for (int cf = 0; cf < 4; ++cf) {
        const int e = (w * 4 + cf) * 16 + l15;
        qg[(size_t)qq * 512 + e] = f2b(acc[qf2][cf][r] * iv);
      }
    }
  }
}

// ================= 128x128 2-phase OUT GEMM (head-split A layout) =================
__global__ __launch_bounds__(256)
void k_gemm_out(const unsigned short* __restrict__ A, const unsigned short* __restrict__ Bt,
                float* __restrict__ C, const float* __restrict__ bias) {
  const int m0 = blockIdx.y * 128;
  const int n0 = blockIdx.x * 128;
  __shared__ __align__(16) unsigned short As[2][128 * 32];
  __shared__ __align__(16) unsigned short Bs[2][128 * 32];
  const int tid = threadIdx.x;
  const int lane = tid & 63;
  const int wm = ((tid >> 6) >> 1) * 64;
  const int wn = ((tid >> 6) & 1) * 64;
  const int srow = tid >> 2;
  const int scol = (tid & 3) * 8;
  f32x4 acc[4][4] = {};

  const int row1 = m0 + srow, row2 = row1 + 64;
  const size_t hb1 = (size_t)(row1 >> 10) * 8 * 524288 + (size_t)(row1 & 1023) * 512;
  const size_t hb2 = (size_t)(row2 >> 10) * 8 * 524288 + (size_t)(row2 & 1023) * 512;
  const unsigned short* gb = Bt + (size_t)(n0 + srow) * 4096 + scol;

#define STAGEO(buf, k0) do {                                                                          \
    const size_t koffA = (size_t)((k0) >> 9) * 524288 + ((k0) & 511) + scol;                          \
    __builtin_amdgcn_global_load_lds((gv_t*)(A + hb1 + koffA), (lv_t*)(&As[buf][tid * 8]), 16, 0, 0);  \
    __builtin_amdgcn_global_load_lds((gv_t*)(A + hb2 + koffA), (lv_t*)(&As[buf][tid * 8 + 2048]), 16, 0, 0); \
    __builtin_amdgcn_global_load_lds((gv_t*)(gb + (k0)), (lv_t*)(&Bs[buf][tid * 8]), 16, 0, 0);        \
    __builtin_amdgcn_global_load_lds((gv_t*)(gb + 64L * 4096 + (k0)), (lv_t*)(&Bs[buf][tid * 8 + 2048]), 16, 0, 0); \
  } while (0)

  STAGEO(0, 0);
  for (int k0 = 0; k0 < 4096; k0 += 32) {
    const int cur = (k0 >> 5) & 1;
    __syncthreads();
    if (k0 + 32 < 4096) { STAGEO(cur ^ 1, k0 + 32); }
    const unsigned short* ap = &As[cur][(wm + (lane & 15)) * 32 + (lane >> 4) * 8];
    const unsigned short* bp = &Bs[cur][(wn + (lane & 15)) * 32 + (lane >> 4) * 8];
    bf16x8 fa[4], fb[4];
#pragma unroll
    for (int i = 0; i < 4; ++i) fa[i] = *(const bf16x8*)(ap + i * 16 * 32);
#pragma unroll
    for (int i = 0; i < 4; ++i) fb[i] = *(const bf16x8*)(bp + i * 16 * 32);
#pragma unroll
    for (int mi = 0; mi < 4; ++mi)
#pragma unroll
      for (int ni = 0; ni < 4; ++ni)
        acc[mi][ni] = __builtin_amdgcn_mfma_f32_16x16x32_bf16(fa[mi], fb[ni], acc[mi][ni], 0, 0, 0);
  }
#undef STAGEO

#pragma unroll
  for (int mi = 0; mi < 4; ++mi) {
#pragma unroll
    for (int ni = 0; ni < 4; ++ni) {
#pragma unroll
      for (int r = 0; r < 4; ++r) {
        const int row = m0 + wm + mi * 16 + ((lane >> 4) * 4 + r);
        const int col = n0 + wn + ni * 16 + (lane & 15);
        C[(long)row * 512 + col] = acc[mi][ni][r] + bias[col];
      }
    }
  }
}

extern "C" void kernel_launch(void* const* d_in, const int* in_sizes, int n_in,
                              void* d_out, int out_size, void* d_ws, size_t ws_size,
                              hipStream_t stream) {
  const float* x  = (const float*)d_in[0];
  const float* Wk = (const float*)d_in[1];
  const float* Wq = (const float*)d_in[2];
  const float* Wv = (const float*)d_in[3];
  const float* Wu = (const float*)d_in[4];
  const float* bu = (const float*)d_in[5];
  float* out = (float*)d_out;
  char* ws = (char*)d_ws;

  // ws layout: wut[0,4M) wtqkv[4M,16M) xb[16M,24M) q[24M,88M) k[88M,152M) vt[152M,216M)
  const size_t NEED = 226492416;  // 216 MB
  if (ws_size < NEED) return;

  unsigned short* wut   = (unsigned short*)(ws + 0);
  unsigned short* wtqkv = (unsigned short*)(ws + 4194304);
  unsigned short* xb    = (unsigned short*)(ws + 16777216);
  unsigned short* qb    = (unsigned short*)(ws + 25165824);  // q; attn output in-place
  unsigned short* kb    = qb + 33554432;
  unsigned short* vtb   = qb + 67108864;

  const float s4 = 0.21022410381342865f;  // 512^(-0.25)

  k_cast<<<4096, 256, 0, stream>>>(x, xb, 1048576);
  k_transpose_cast3<<<dim3(128, 16, 3), dim3(32, 8), 0, stream>>>(Wq, Wk, Wv, wtqkv, 512, 4096);
  k_transpose_cast<<<dim3(16, 128), dim3(32, 8), 0, stream>>>(Wu, wut, 4096, 512);

  // q,k = x @ [Wq|Wk] (M=8192, N=8192, K=512), scaled, scattered to [bh][t][e]
  k_gemm256<EPI_QK><<<dim3(32, 32, 1), 512, 0, stream>>>(xb, wtqkv, qb, 512, 512, 512, s4);
  // vt = Wv^T @ x^T (M=4096, N=8192, K=512) -> [bh][e][t]
  k_gemm256<EPI_VT><<<dim3(32, 16, 1), 512, 0, stream>>>(wtqkv + 4194304, xb, vtb, 512, 512, 512, 1.0f);

  // fused attention: per (head, 64-row q-tile); output over q in [bh][t][e]
  k_attn<<<1024, 512, 0, stream>>>(qb, kb, vtb);

  // out = ao @ Wu + bu (M=8192, N=512, K=4096), A in head-split layout
  k_gemm_out<<<dim3(4, 64, 1), 256, 0, stream>>>(qb, wut, out, bu);
}

// Round 18
// 466.240 us; speedup vs baseline: 1.7975x; 1.0186x over previous
//
#include <hip/hip_runtime.h>
#include <hip/hip_bf16.h>
#include <cstdint>

typedef __attribute__((ext_vector_type(8))) short bf16x8;
typedef __attribute__((ext_vector_type(4))) float f32x4;

typedef __attribute__((address_space(1))) const void gv_t;
typedef __attribute__((address_space(3))) void lv_t;

__device__ __forceinline__ unsigned short f2b(float f) {
  __hip_bfloat16 h = __float2bfloat16(f);
  return __builtin_bit_cast(unsigned short, h);
}
__device__ __forceinline__ float b2f(unsigned short u) {
  unsigned int x = (unsigned int)u << 16;
  return __builtin_bit_cast(float, x);
}

// ---------- cast fp32 -> bf16 (vectorized x4) ----------
__global__ __launch_bounds__(256) void k_cast(const float* __restrict__ src,
                                              unsigned short* __restrict__ dst, int n4) {
  int i = blockIdx.x * 256 + threadIdx.x;
  if (i >= n4) return;
  const float4 v = ((const float4*)src)[i];
  ushort4 o;
  o.x = f2b(v.x); o.y = f2b(v.y); o.z = f2b(v.z); o.w = f2b(v.w);
  ((ushort4*)dst)[i] = o;
}

// ---------- transpose + cast: dst[c*R + r] = bf16(src[r*C + c]) ----------
__global__ void k_transpose_cast(const float* __restrict__ src,
                                 unsigned short* __restrict__ dst, int R, int C) {
  __shared__ float tile[32][33];
  const int tx = threadIdx.x, ty = threadIdx.y;
  const int c0 = blockIdx.x * 32, r0 = blockIdx.y * 32;
#pragma unroll
  for (int i = 0; i < 32; i += 8)
    tile[ty + i][tx] = src[(long)(r0 + ty + i) * C + (c0 + tx)];
  __syncthreads();
#pragma unroll
  for (int i = 0; i < 32; i += 8)
    dst[(long)(c0 + ty + i) * R + (r0 + tx)] = f2b(tile[tx][ty + i]);
}

// ---------- merged transpose+cast for 3 same-shape weights (z selects) ----------
__global__ void k_transpose_cast3(const float* __restrict__ s0, const float* __restrict__ s1,
                                  const float* __restrict__ s2,
                                  unsigned short* __restrict__ dst, int R, int C) {
  const float* src = (blockIdx.z == 0) ? s0 : ((blockIdx.z == 1) ? s1 : s2);
  unsigned short* d = dst + (size_t)blockIdx.z * R * C;
  __shared__ float tile[32][33];
  const int tx = threadIdx.x, ty = threadIdx.y;
  const int c0 = blockIdx.x * 32, r0 = blockIdx.y * 32;
#pragma unroll
  for (int i = 0; i < 32; i += 8)
    tile[ty + i][tx] = src[(long)(r0 + ty + i) * C + (c0 + tx)];
  __syncthreads();
#pragma unroll
  for (int i = 0; i < 32; i += 8)
    d[(long)(c0 + ty + i) * R + (r0 + tx)] = f2b(tile[tx][ty + i]);
}

enum { EPI_QK = 0, EPI_VT = 1 };

// ================= 256x256 8-phase engine (T2+T3+T4+T5) — QK & VT =================
#define BAR256() do { asm volatile("" ::: "memory"); __builtin_amdgcn_s_barrier(); asm volatile("" ::: "memory"); } while (0)
#define WAITVM(n) do { asm volatile("s_waitcnt vmcnt(" #n ")" ::: "memory"); __builtin_amdgcn_sched_barrier(0); } while (0)
#define WAITLG() do { asm volatile("s_waitcnt lgkmcnt(0)" ::: "memory"); } while (0)

#define STAGE_A(tt, hw, qq)                                                                     \
  __builtin_amdgcn_global_load_lds(                                                            \
    (gv_t*)(A + (long)(m0 + (hw)*128 + (qq)*64 + rr) * lda + ((tt) << 6) + csw),               \
    (lv_t*)(&L[(((((tt)&1)*2 + (hw))*128 + (qq)*64 + rr))*64 + c0]), 16, 0, 0)

#define STAGE_B(tt, qi)                                                                         \
  __builtin_amdgcn_global_load_lds(                                                            \
    (gv_t*)(Bt + (long)(n0 + (qi)*64 + rr) * ldb + ((tt) << 6) + csw),                         \
    (lv_t*)(&L[32768 + (((((tt)&1)*2 + ((qi)>>1))*128 + ((qi)&1)*64 + rr))*64 + c0]), 16, 0, 0)

#define PHASE(slot, QR, QC) do {                                                                \
    const unsigned short* Abase = &L[((slot)*2 + wr) * 8192];                                   \
    const unsigned short* Bbase = &L[32768 + ((slot)*2 + (wc>>1)) * 8192];                      \
    bf16x8 afr[4][2], bfr[2][2];                                                                \
    _Pragma("unroll")                                                                           \
    for (int fr = 0; fr < 4; ++fr) {                                                            \
      const int rA = (QR)*64 + fr*16 + l15;                                                     \
      _Pragma("unroll")                                                                         \
      for (int kk = 0; kk < 2; ++kk) {                                                          \
        const int cA = (kk*32 + l4*8) ^ ((rA & 7) << 3);                                        \
        afr[fr][kk] = *(const bf16x8*)(Abase + rA*64 + cA);                                     \
      }                                                                                         \
    }                                                                                           \
    _Pragma("unroll")                                                                           \
    for (int fc = 0; fc < 2; ++fc) {                                                            \
      const int rB = (wc&1)*64 + (QC)*32 + fc*16 + l15;                                         \
      _Pragma("unroll")                                                                         \
      for (int kk = 0; kk < 2; ++kk) {                                                          \
        const int cB = (kk*32 + l4*8) ^ ((rB & 7) << 3);                                        \
        bfr[fc][kk] = *(const bf16x8*)(Bbase + rB*64 + cB);                                     \
      }                                                                                         \
    }                                                                                           \
    __builtin_amdgcn_s_setprio(1);                                                              \
    _Pragma("unroll")                                                                           \
    for (int fr = 0; fr < 4; ++fr)                                                              \
      _Pragma("unroll")                                                                         \
      for (int fc = 0; fc < 2; ++fc)                                                            \
        _Pragma("unroll")                                                                       \
        for (int kk = 0; kk < 2; ++kk)                                                          \
          acc[(QR)*4+fr][(QC)*2+fc] = __builtin_amdgcn_mfma_f32_16x16x32_bf16(                  \
              afr[fr][kk], bfr[fc][kk], acc[(QR)*4+fr][(QC)*2+fc], 0, 0, 0);                    \
    __builtin_amdgcn_s_setprio(0);                                                              \
  } while (0)

template <int EPI>
__global__ __launch_bounds__(512)
void k_gemm256(const unsigned short* __restrict__ A, const unsigned short* __restrict__ Bt,
               void* __restrict__ Cv, int K, int lda, int ldb, float scale) {
  const int m0 = blockIdx.y * 256;
  const int n0 = blockIdx.x * 256;
  __shared__ __align__(16) unsigned short L[65536];
  const int tid = threadIdx.x;
  const int lane = tid & 63;
  const int wid = tid >> 6;
  const int wr = wid >> 2;
  const int wc = wid & 3;
  const int l15 = lane & 15;
  const int l4 = lane >> 4;
  const int rr = tid >> 3;
  const int c0 = (tid & 7) * 8;
  const int csw = c0 ^ ((rr & 7) << 3);

  f32x4 acc[8][4] = {};
  const int NT = K >> 6;

  STAGE_A(0, 0, 0); STAGE_A(0, 1, 0); STAGE_A(0, 0, 1); STAGE_A(0, 1, 1);
  STAGE_B(0, 0); STAGE_B(0, 1); STAGE_B(0, 2); STAGE_B(0, 3);
  if (NT > 1) {
    STAGE_A(1, 0, 0); STAGE_A(1, 1, 0);
    WAITVM(2);
  } else {
    WAITVM(0);
  }
  __builtin_amdgcn_s_barrier();
  asm volatile("" ::: "memory");

  for (int t = 0; t < NT; ++t) {
    const int slot = t & 1;
    if (t + 1 < NT) { STAGE_A(t + 1, 0, 1); STAGE_A(t + 1, 1, 1); }
    PHASE(slot, 0, 0);
    BAR256();
    if (t + 1 < NT) { STAGE_B(t + 1, 0); STAGE_B(t + 1, 1); }
    PHASE(slot, 0, 1);
    BAR256();
    if (t + 1 < NT) { STAGE_B(t + 1, 2); STAGE_B(t + 1, 3); }
    if (t + 2 < NT) { STAGE_A(t + 2, 0, 0); STAGE_A(t + 2, 1, 0); }
    PHASE(slot, 1, 0);
    BAR256();
    PHASE(slot, 1, 1);
    if (t + 1 < NT) {
      if (t + 2 < NT) WAITVM(2);
      else            WAITVM(0);
      __builtin_amdgcn_s_barrier();
      asm volatile("" ::: "memory");
    }
  }

#pragma unroll
  for (int i = 0; i < 8; ++i) {
#pragma unroll
    for (int j = 0; j < 4; ++j) {
#pragma unroll
      for (int r = 0; r < 4; ++r) {
        const int row = m0 + wr * 128 + i * 16 + l4 * 4 + r;
        const int col = n0 + wc * 64 + j * 16 + l15;
        const float v = acc[i][j][r];
        if (EPI == EPI_QK) {
          unsigned short* o = (unsigned short*)Cv;
          const int sec = col >> 12;
          const int cc = col & 4095;
          const long addr = (long)sec * 33554432 +
              ((long)((row >> 10) * 8 + (cc >> 9)) * 1024 + (row & 1023)) * 512 + (cc & 511);
          o[addr] = f2b(v * scale);
        } else {  // EPI_VT
          unsigned short* o = (unsigned short*)Cv;
          const long addr = (long)((col >> 10) * 8 + (row >> 9)) * 524288 +
                            (long)(row & 511) * 1024 + (col & 1023);
          o[addr] = f2b(v);
        }
      }
    }
  }
}

// ================= fused attention: r13 exact (best measured: 262 us) =================
// KT=32, 64 q-rows, 8 waves; Ks dbuf padded-520 (aligned, 8-touches/bank);
// Vs grouped 544-stride; Es 40-stride; counted vmcnt(4); Q hoisted to regs.
#define KLD 520     // Ks padded row stride (shorts), 16B-aligned
#define VGRP 544    // Vs group stride (shorts)

__device__ __forceinline__ void stage_k(const unsigned short* kg, unsigned short* dst,
                                        int c, int w, int lane) {
#pragma unroll
  for (int i = 0; i < 4; ++i) {
    const int row = i * 8 + w;
    __builtin_amdgcn_global_load_lds(
        (gv_t*)(kg + (size_t)(c * 32 + row) * 512 + lane * 8),
        (lv_t*)(dst + row * KLD + lane * 8), 16, 0, 0);
  }
}
__device__ __forceinline__ void stage_v(const unsigned short* vg, unsigned short* dst,
                                        int c, int w, int lane) {
#pragma unroll
  for (int i = 0; i < 4; ++i) {
    const int G = i * 8 + w;                 // group = 16 e-rows
    const int e = G * 16 + (lane >> 2);
    __builtin_amdgcn_global_load_lds(
        (gv_t*)(vg + (size_t)e * 1024 + c * 32 + (lane & 3) * 8),
        (lv_t*)(dst + G * VGRP + lane * 8), 16, 0, 0);
  }
}

__global__ __launch_bounds__(512)
void k_attn(unsigned short* __restrict__ q,        // [64][1024][512] in/out
            const unsigned short* __restrict__ k,  // [64][1024][512]
            const unsigned short* __restrict__ vt) // [64][512][1024]
{
  __shared__ __align__(16) unsigned short Ks[2][32 * KLD];   // 65KB
  __shared__ __align__(16) unsigned short Vs[2][32 * VGRP];  // 68KB
  __shared__ __align__(16) unsigned short Es[2][2560];       // 10KB, stride 40
  const int bid = blockIdx.x;
  const int head = (bid & 7) * 8 + ((bid >> 3) >> 4);  // 16 same-head blocks per XCD
  const int qt = (bid >> 3) & 15;
  const int tid = threadIdx.x;
  const int w = tid >> 6, lane = tid & 63;
  const int l15 = lane & 15, l4 = lane >> 4;
  const int qf = w & 3, kf = w >> 2;

  unsigned short* qg = q + (size_t)(head * 1024 + qt * 64) * 512;
  const unsigned short* kg = k + (size_t)head * 524288;
  const unsigned short* vg = vt + (size_t)head * 524288;

  const int qrow = qf * 16 + l15;
  const int krow = kf * 16 + l15;

  // Q-hoist: lane's 16 slices of its q-row
  bf16x8 q_r[16];
#pragma unroll
  for (int ks = 0; ks < 16; ++ks)
    q_r[ks] = *(const bf16x8*)(qg + (size_t)qrow * 512 + (size_t)(ks * 4 + l4) * 8);

  // prologue: K(0), V(0), K(1)  (12 loads in flight)
  stage_k(kg, &Ks[0][0], 0, w, lane);
  stage_v(vg, &Vs[0][0], 0, w, lane);
  stage_k(kg, &Ks[1][0], 1, w, lane);

  f32x4 acc[4][4] = {};
  float partial = 0.f;
  const int erow = tid >> 3;
  const int ej = tid & 7;
  const int eidx = 40 * erow + ej * 4;

  for (int c = 0; c < 32; ++c) {
    unsigned short* KsC = &Ks[c & 1][0];
    unsigned short* VsC = &Vs[c & 1][0];
    unsigned short* EsC = &Es[c & 1][0];
    // top barrier: K(c),V(c) landed; K(c+1) stays in flight
    if (c < 31) { WAITVM(4); } else { WAITVM(0); }
    WAITLG();
    __builtin_amdgcn_s_barrier();
    asm volatile("" ::: "memory");
    // issue V(c+1) (overwrites V(c-1); readers finished before this barrier)
    if (c + 1 < 32) stage_v(vg, &Vs[(c + 1) & 1][0], c + 1, w, lane);
    // QK(c): A = q_r (regs), B = Ks (padded, linear); 2 independent chains
    f32x4 sacc0 = {0.f, 0.f, 0.f, 0.f};
    f32x4 sacc1 = {0.f, 0.f, 0.f, 0.f};
    __builtin_amdgcn_s_setprio(1);
#pragma unroll
    for (int ks = 0; ks < 16; ks += 2) {
      bf16x8 bk0 = *(const bf16x8*)(&KsC[krow * KLD + (ks * 4 + l4) * 8]);
      sacc0 = __builtin_amdgcn_mfma_f32_16x16x32_bf16(q_r[ks], bk0, sacc0, 0, 0, 0);
      bf16x8 bk1 = *(const bf16x8*)(&KsC[krow * KLD + ((ks + 1) * 4 + l4) * 8]);
      sacc1 = __builtin_amdgcn_mfma_f32_16x16x32_bf16(q_r[ks + 1], bk1, sacc1, 0, 0, 0);
    }
    __builtin_amdgcn_s_setprio(0);
#pragma unroll
    for (int r = 0; r < 4; ++r) {
      const int qq = qf * 16 + l4 * 4 + r;      // S frag: row=q, col=k
      const int kk2 = kf * 16 + l15;
      EsC[40 * qq + kk2] = f2b(__expf(sacc0[r] + sacc1[r]));
    }
    // mid barrier: publish Es; all QK(c) K-readers done
    WAITLG();
    __builtin_amdgcn_s_barrier();
    asm volatile("" ::: "memory");
    // issue K(c+2) (overwrites K(c); readers finished at mid barrier)
    if (c + 2 < 32) stage_k(kg, KsC, c + 2, w, lane);
    // rowsum partial
    {
      const ushort4 ev = *(const ushort4*)(&EsC[eidx]);
      partial += (b2f(ev.x) + b2f(ev.y)) + (b2f(ev.z) + b2f(ev.w));
    }
    // PV(c): grouped Vs reads (group = w*4+cf, row = l15, slice l4)
    bf16x8 bv[4];
#pragma unroll
    for (int cf = 0; cf < 4; ++cf) {
      const int G = w * 4 + cf;
      bv[cf] = *(const bf16x8*)(&VsC[G * VGRP + l15 * 32 + l4 * 8]);
    }
    __builtin_amdgcn_s_setprio(1);
#pragma unroll
    for (int qf2 = 0; qf2 < 4; ++qf2) {
      const int qq = qf2 * 16 + l15;
      bf16x8 ae = *(const bf16x8*)(&EsC[40 * qq + 8 * l4]);
#pragma unroll
      for (int cf = 0; cf < 4; ++cf)
        acc[qf2][cf] = __builtin_amdgcn_mfma_f32_16x16x32_bf16(ae, bv[cf], acc[qf2][cf], 0, 0, 0);
    }
    __builtin_amdgcn_s_setprio(0);
  }

  // rowsum reduce -> 1/rs  (Ks dead; reuse as float scratch)
  __syncthreads();
  float* fs = (float*)&Ks[0][0];
  fs[tid] = partial;
  __syncthreads();
  if (tid < 64) {
    float s = 0.f;
#pragma unroll
    for (int j = 0; j < 8; ++j) s += fs[tid * 8 + j];
    fs[512 + tid] = 1.0f / s;
  }
  __syncthreads();

  // epilogue: out = acc/rs, overwrite own q rows ([bh][t][e] layout)
  // PV B-frag = V rows of group G=w*4+cf, row l15 -> e = G*16 + l15.
#pragma unroll
  for (int qf2 = 0; qf2 < 4; ++qf2) {
#pragma unroll
    for (int r = 0; r < 4; ++r) {
      const int qq = qf2 * 16 + l4 * 4 + r;
      const float iv = fs[512 + qq];
#pragma unroll
      for (int cf = 0; cf < 4; ++cf) {
        const int e = (w * 4 + cf) * 16 + l15;
        qg[(size_t)qq * 512 + e] = f2b(acc[qf2][cf][r] * iv);
      }
    }
  }
}

// ================= 128x128 2-phase OUT GEMM (head-split A layout) =================
__global__ __launch_bounds__(256)
void k_gemm_out(const unsigned short* __restrict__ A, const unsigned short* __restrict__ Bt,
                float* __restrict__ C, const float* __restrict__ bias) {
  const int m0 = blockIdx.y * 128;
  const int n0 = blockIdx.x * 128;
  __shared__ __align__(16) unsigned short As[2][128 * 32];
  __shared__ __align__(16) unsigned short Bs[2][128 * 32];
  const int tid = threadIdx.x;
  const int lane = tid & 63;
  const int wm = ((tid >> 6) >> 1) * 64;
  const int wn = ((tid >> 6) & 1) * 64;
  const int srow = tid >> 2;
  const int scol = (tid & 3) * 8;
  f32x4 acc[4][4] = {};

  const int row1 = m0 + srow, row2 = row1 + 64;
  const size_t hb1 = (size_t)(row1 >> 10) * 8 * 524288 + (size_t)(row1 & 1023) * 512;
  const size_t hb2 = (size_t)(row2 >> 10) * 8 * 524288 + (size_t)(row2 & 1023) * 512;
  const unsigned short* gb = Bt + (size_t)(n0 + srow) * 4096 + scol;

#define STAGEO(buf, k0) do {                                                                          \
    const size_t koffA = (size_t)((k0) >> 9) * 524288 + ((k0) & 511) + scol;                          \
    __builtin_amdgcn_global_load_lds((gv_t*)(A + hb1 + koffA), (lv_t*)(&As[buf][tid * 8]), 16, 0, 0);  \
    __builtin_amdgcn_global_load_lds((gv_t*)(A + hb2 + koffA), (lv_t*)(&As[buf][tid * 8 + 2048]), 16, 0, 0); \
    __builtin_amdgcn_global_load_lds((gv_t*)(gb + (k0)), (lv_t*)(&Bs[buf][tid * 8]), 16, 0, 0);        \
    __builtin_amdgcn_global_load_lds((gv_t*)(gb + 64L * 4096 + (k0)), (lv_t*)(&Bs[buf][tid * 8 + 2048]), 16, 0, 0); \
  } while (0)

  STAGEO(0, 0);
  for (int k0 = 0; k0 < 4096; k0 += 32) {
    const int cur = (k0 >> 5) & 1;
    __syncthreads();
    if (k0 + 32 < 4096) { STAGEO(cur ^ 1, k0 + 32); }
    const unsigned short* ap = &As[cur][(wm + (lane & 15)) * 32 + (lane >> 4) * 8];
    const unsigned short* bp = &Bs[cur][(wn + (lane & 15)) * 32 + (lane >> 4) * 8];
    bf16x8 fa[4], fb[4];
#pragma unroll
    for (int i = 0; i < 4; ++i) fa[i] = *(const bf16x8*)(ap + i * 16 * 32);
#pragma unroll
    for (int i = 0; i < 4; ++i) fb[i] = *(const bf16x8*)(bp + i * 16 * 32);
#pragma unroll
    for (int mi = 0; mi < 4; ++mi)
#pragma unroll
      for (int ni = 0; ni < 4; ++ni)
        acc[mi][ni] = __builtin_amdgcn_mfma_f32_16x16x32_bf16(fa[mi], fb[ni], acc[mi][ni], 0, 0, 0);
  }
#undef STAGEO

#pragma unroll
  for (int mi = 0; mi < 4; ++mi) {
#pragma unroll
    for (int ni = 0; ni < 4; ++ni) {
#pragma unroll
      for (int r = 0; r < 4; ++r) {
        const int row = m0 + wm + mi * 16 + ((lane >> 4) * 4 + r);
        const int col = n0 + wn + ni * 16 + (lane & 15);
        C[(long)row * 512 + col] = acc[mi][ni][r] + bias[col];
      }
    }
  }
}

extern "C" void kernel_launch(void* const* d_in, const int* in_sizes, int n_in,
                              void* d_out, int out_size, void* d_ws, size_t ws_size,
                              hipStream_t stream) {
  const float* x  = (const float*)d_in[0];
  const float* Wk = (const float*)d_in[1];
  const float* Wq = (const float*)d_in[2];
  const float* Wv = (const float*)d_in[3];
  const float* Wu = (const float*)d_in[4];
  const float* bu = (const float*)d_in[5];
  float* out = (float*)d_out;
  char* ws = (char*)d_ws;

  // ws layout: wut[0,4M) wtqkv[4M,16M) xb[16M,24M) q[24M,88M) k[88M,152M) vt[152M,216M)
  const size_t NEED = 226492416;  // 216 MB
  if (ws_size < NEED) return;

  unsigned short* wut   = (unsigned short*)(ws + 0);
  unsigned short* wtqkv = (unsigned short*)(ws + 4194304);
  unsigned short* xb    = (unsigned short*)(ws + 16777216);
  unsigned short* qb    = (unsigned short*)(ws + 25165824);  // q; attn output in-place
  unsigned short* kb    = qb + 33554432;
  unsigned short* vtb   = qb + 67108864;

  const float s4 = 0.21022410381342865f;  // 512^(-0.25)

  k_cast<<<4096, 256, 0, stream>>>(x, xb, 1048576);
  k_transpose_cast3<<<dim3(128, 16, 3), dim3(32, 8), 0, stream>>>(Wq, Wk, Wv, wtqkv, 512, 4096);
  k_transpose_cast<<<dim3(16, 128), dim3(32, 8), 0, stream>>>(Wu, wut, 4096, 512);

  // q,k = x @ [Wq|Wk] (M=8192, N=8192, K=512), scaled, scattered to [bh][t][e]
  k_gemm256<EPI_QK><<<dim3(32, 32, 1), 512, 0, stream>>>(xb, wtqkv, qb, 512, 512, 512, s4);
  // vt = Wv^T @ x^T (M=4096, N=8192, K=512) -> [bh][e][t]
  k_gemm256<EPI_VT><<<dim3(32, 16, 1), 512, 0, stream>>>(wtqkv + 4194304, xb, vtb, 512, 512, 512, 1.0f);

  // fused attention: per (head, 64-row q-tile); output over q in [bh][t][e]
  k_attn<<<1024, 512, 0, stream>>>(qb, kb, vtb);

  // out = ao @ Wu + bu (M=8192, N=512, K=4096), A in head-split layout
  k_gemm_out<<<dim3(4, 64, 1), 256, 0, stream>>>(qb, wut, out, bu);
}